// Round 6
// baseline (29.062 us; speedup 1.0000x reference)
//
#include <hip/hip_runtime.h>

// NeuralPonds: flavor = int(abs(np-pairwise-sum over d_model)) % 10000,
// out[token] = tables[pond[token], flavor]  (row of 1024 f32)
//
// Bit-exact numpy pairwise sum (verified on HW, absmax 0.0): 64 sequential
// chains r[b][j] = sum_k a[b*128 + j + 8k] (numpy accumulation order)
// combined by a balanced binary tree == 64-lane shfl_xor butterfly.
//
// Ladder: R1 fused strided 30.1 | R2 fused +LDS 30.0 | R3 split (LDS k1,
// barrier) 27.8 | R4 split strided k1 29.4 (coalesced f4 loads required in
// pure-read kernel) | R5 wave-local fence 28.0 (= R3, barrier was free).
//
// R6: persistent grid (2048 blocks), 2 tokens per wave via stride loop in
// both kernels -> halves dispatch rounds, software-pipelines token t+1's
// global loads under token t's compute. k1 uses two LDS sub-regions per
// wave (A/B per iteration): no WAR hazard, still barrier-free.

#define POND_MOD 10000
#define D_MODEL  1024
#define PADDED   132            // 128 + 4 pad floats per 128-elem sub-block
#define REGION   (8 * PADDED)   // 1056 floats per token-transpose region
#define NBLOCKS  2048

typedef float f32x4 __attribute__((ext_vector_type(4)));

__global__ __launch_bounds__(256) void np_flavor_kernel(
    const float* __restrict__ ctx,      // [ntok, 1024]
    const int*   __restrict__ pond,     // [ntok]
    int*         __restrict__ idxbuf,   // [ntok] combined pond*10000+flavor
    int ntok)
{
    __shared__ float lds[4 * 2 * REGION];         // 4 waves x 2 iter-regions

    const int lane   = threadIdx.x & 63;
    const int wid    = threadIdx.x >> 6;
    const int wave   = blockIdx.x * 4 + wid;
    const int nwaves = NBLOCKS * 4;

    const int l31 = lane & 31;
    const int hb  = lane >> 5;
    const int b   = lane >> 3;
    const int j   = lane & 7;

    int iter = 0;
    for (int token = wave; token < ntok; token += nwaves, ++iter) {
        // coalesced nontemporal load of the 4KB ctx row
        const f32x4* row4 = (const f32x4*)(ctx + (size_t)token * D_MODEL);
        const int pd = pond[token];
        f32x4 v[4];
        #pragma unroll
        for (int t = 0; t < 4; ++t)
            v[t] = __builtin_nontemporal_load(&row4[t * 64 + lane]);

        // transpose into this wave's region for this iteration (A/B)
        float* w = lds + (wid * 2 + (iter & 1)) * REGION;
        #pragma unroll
        for (int t = 0; t < 4; ++t)
            *(f32x4*)(w + (2 * t + hb) * PADDED + 4 * l31) = v[t];

        // wave-local visibility: DS ops are wave-wide; draining lgkmcnt
        // makes all 64 lanes' writes visible within the wave. No barrier.
        asm volatile("s_waitcnt lgkmcnt(0)" ::: "memory");
        __builtin_amdgcn_sched_barrier(0);

        // numpy-order chain: lane l = 8b + j sums a[b*128 + j + 8k]
        const float* rp = w + b * PADDED + j;
        float r = rp[0];
        #pragma unroll
        for (int k = 1; k < 16; ++k)
            r += rp[8 * k];

        // balanced-binary-tree combine == numpy pairwise tree
        #pragma unroll
        for (int m = 1; m < 64; m <<= 1)
            r += __shfl_xor(r, m, 64);

        if (lane == 0) {
            const int flavor = ((int)fabsf(r)) % POND_MOD;
            idxbuf[token] = pd * POND_MOD + flavor;
        }
    }
}

__global__ __launch_bounds__(256) void np_gather_kernel(
    const float* __restrict__ tables,   // [10*10000, 1024]
    const int*   __restrict__ idxbuf,   // [ntok]
    float*       __restrict__ out,      // [ntok, 1024]
    int ntok)
{
    const int lane   = threadIdx.x & 63;
    const int wid    = threadIdx.x >> 6;
    const int wave   = blockIdx.x * 4 + wid;
    const int nwaves = NBLOCKS * 4;

    for (int token = wave; token < ntok; token += nwaves) {
        const int idx = __builtin_amdgcn_readfirstlane(idxbuf[token]);
        const f32x4* src = (const f32x4*)(tables + (size_t)idx * D_MODEL);
        f32x4*       dst = (f32x4*)(out + (size_t)token * D_MODEL);

        #pragma unroll
        for (int k = 0; k < 4; ++k) {
            f32x4 v = src[k * 64 + lane];                        // hot rows: L2/L3
            __builtin_nontemporal_store(v, &dst[k * 64 + lane]); // stream out
        }
    }
}

// fallback single kernel (ws too small) — R1-verified path
__global__ __launch_bounds__(256) void np_fused_kernel(
    const float* __restrict__ ctx, const int* __restrict__ pond,
    const float* __restrict__ tables, float* __restrict__ out, int ntok)
{
    const int lane  = threadIdx.x & 63;
    const int wid   = threadIdx.x >> 6;
    const int token = blockIdx.x * 4 + wid;
    if (token >= ntok) return;

    const float* row = ctx + (size_t)token * D_MODEL;
    const int b = lane >> 3, j = lane & 7;
    const float* p = row + b * 128 + j;
    float r = p[0];
    #pragma unroll
    for (int k = 1; k < 16; ++k) r += p[8 * k];
    #pragma unroll
    for (int m = 1; m < 64; m <<= 1) r += __shfl_xor(r, m, 64);

    const int flavor = ((int)fabsf(r)) % POND_MOD;
    const int pd = pond[token];
    const float4* src = (const float4*)(tables + ((size_t)pd * POND_MOD + flavor) * D_MODEL);
    float4*       dst = (float4*)(out + (size_t)token * D_MODEL);
    #pragma unroll
    for (int k = 0; k < 4; ++k) dst[k * 64 + lane] = src[k * 64 + lane];
}

extern "C" void kernel_launch(void* const* d_in, const int* in_sizes, int n_in,
                              void* d_out, int out_size, void* d_ws, size_t ws_size,
                              hipStream_t stream) {
    const float* ctx    = (const float*)d_in[0];
    const int*   pond   = (const int*)d_in[1];
    const float* tables = (const float*)d_in[2];
    float*       out    = (float*)d_out;

    const int ntok = in_sizes[1];                 // 16384 tokens

    if (ws_size >= (size_t)ntok * sizeof(int)) {
        int* idxbuf = (int*)d_ws;
        np_flavor_kernel<<<NBLOCKS, 256, 0, stream>>>(ctx, pond, idxbuf, ntok);
        np_gather_kernel<<<NBLOCKS, 256, 0, stream>>>(tables, idxbuf, out, ntok);
    } else {
        const int blocks = (ntok + 3) / 4;
        np_fused_kernel<<<blocks, 256, 0, stream>>>(ctx, pond, tables, out, ntok);
    }
}